// Round 1
// 584.985 us; speedup vs baseline: 1.1561x; 1.1561x over previous
//
#include <hip/hip_runtime.h>

#define N_ROWS 32768
#define HDIM 1024
#define NCLS 1000
#define CPAD 1024
#define NOUT 1024
#define KK2 2048

typedef __attribute__((ext_vector_type(8))) unsigned short ushort8v;
typedef __attribute__((ext_vector_type(4))) unsigned short ushort4v;
typedef __attribute__((ext_vector_type(8))) _Float16 f16x8;
typedef __attribute__((ext_vector_type(4))) float f32x4;

__device__ inline unsigned short h_bits(_Float16 h) {
  union { _Float16 h; unsigned short u; } c; c.h = h; return c.u;
}

__device__ inline unsigned long long shfl_xor_u64(unsigned long long v, int m) {
  int lo = __shfl_xor((int)(unsigned)(v & 0xFFFFFFFFull), m, 64);
  int hi = __shfl_xor((int)(unsigned)(v >> 32), m, 64);
  return ((unsigned long long)(unsigned)hi << 32) | (unsigned)lo;
}

// async global -> LDS, 16B per lane. LDS dest is wave-uniform base + lane*16.
__device__ __forceinline__ void gload16(const void* g, void* l) {
  __builtin_amdgcn_global_load_lds(
      (__attribute__((address_space(1))) void*)g,
      (__attribute__((address_space(3))) void*)l, 16, 0, 0);
}

__global__ __launch_bounds__(256) void init_keys_kernel(unsigned long long* __restrict__ keys) {
  keys[(size_t)blockIdx.x * 256 + threadIdx.x] = 0ull;
}

// One block per (padded) anchor row: norm, scale by 1024/max(norm,eps), fp16 hi/lo split.
__global__ __launch_bounds__(256) void prep_anchors_kernel(
    const float* __restrict__ anchors, unsigned short* __restrict__ ash,
    unsigned short* __restrict__ asl, unsigned short* __restrict__ anh) {
  int c = blockIdx.x;
  int t = threadIdx.x;
  float v[4];
  float ss = 0.f;
  if (c < NCLS) {
    for (int i = 0; i < 4; i++) {
      v[i] = anchors[(size_t)c * HDIM + (i << 8) + t];
      ss += v[i] * v[i];
    }
  } else {
    v[0] = v[1] = v[2] = v[3] = 0.f;
  }
  for (int m = 1; m < 64; m <<= 1) ss += __shfl_xor(ss, m, 64);
  __shared__ float wsum[4];
  if ((t & 63) == 0) wsum[t >> 6] = ss;
  __syncthreads();
  float tot = wsum[0] + wsum[1] + wsum[2] + wsum[3];
  // scale by 1024 so the fp16 "lo" part stays clear of subnormals; argmax-invariant
  float scale = 1024.0f / fmaxf(sqrtf(tot), 1e-8f);
  for (int i = 0; i < 4; i++) {
    float x = v[i] * scale;
    _Float16 hi = (_Float16)x;
    float lo = x - (float)hi;
    size_t o = (size_t)c * HDIM + (i << 8) + t;
    ash[o] = h_bits(hi);
    asl[o] = h_bits((_Float16)lo);
    anh[o] = h_bits((_Float16)v[i]);
  }
}

// features fp32 -> fp16 hi + fp16 lo, vectorized
__global__ __launch_bounds__(256) void fsplit_kernel(const float* __restrict__ f,
    unsigned short* __restrict__ fh, unsigned short* __restrict__ fl) {
  size_t i = (size_t)blockIdx.x * 256 + threadIdx.x;
  float4 v = reinterpret_cast<const float4*>(f)[i];
  float xs[4] = {v.x, v.y, v.z, v.w};
  ushort4v h, l;
  for (int j = 0; j < 4; j++) {
    _Float16 hi = (_Float16)xs[j];
    float lo = xs[j] - (float)hi;
    h[j] = h_bits(hi);
    l[j] = h_bits((_Float16)lo);
  }
  reinterpret_cast<ushort4v*>(fh)[i] = h;
  reinterpret_cast<ushort4v*>(fl)[i] = l;
}

// W [2048,1024] fp32 row-major -> Wt [1024,2048] fp16 (k contiguous), via LDS transpose
__global__ __launch_bounds__(256) void wtrans_kernel(const float* __restrict__ W,
                                                     unsigned short* __restrict__ Wt) {
  __shared__ float tile[64][65];
  int kb = (blockIdx.x >> 4) << 6;  // 32 k-tiles
  int nb = (blockIdx.x & 15) << 6;  // 16 n-tiles
  int t = threadIdx.x;
  int tc = t & 63, tr = t >> 6;
  for (int i = 0; i < 16; i++) {
    int r = (i << 2) + tr;
    tile[r][tc] = W[(size_t)(kb + r) * NOUT + nb + tc];
  }
  __syncthreads();
  for (int i = 0; i < 16; i++) {
    int r = (i << 2) + tr;
    Wt[(size_t)(nb + r) * KK2 + kb + tc] = h_bits((_Float16)tile[tc][r]);
  }
}

enum { MODE_OUT = 0, MODE_SIM = 1, MODE_MAIN = 2 };

// C = A (M x K, k-contig) * B^T (rows of B are k-contig), 128x128 tile, 4 waves,
// 16x16x32 f16 MFMA. Staging via global_load_lds (width 16) into linear [128][32] LDS.
// MODE_SIM: 3-term hi/lo product + packed-key atomic argmax.
// MODE_MAIN: epilogue adds aproj[idx[row]].
template <int MODE>
__global__ __launch_bounds__(256) void gemm_kernel(
    const unsigned short* __restrict__ Ahi, const unsigned short* __restrict__ Alo,
    const unsigned short* __restrict__ Bhi, const unsigned short* __restrict__ Blo,
    int lda, int ldb, int bkoff, int NT,
    float* __restrict__ Dout, int ldd,
    unsigned long long* __restrict__ keys,
    const float* __restrict__ aproj,
    float* __restrict__ out) {
  constexpr bool SPLIT = (MODE == MODE_SIM);
  // linear layout: row-major [128][32] f16, required by global_load_lds (no padding)
  __shared__ unsigned short sA[SPLIT ? 2 : 1][128 * 32];
  __shared__ unsigned short sB[SPLIT ? 2 : 1][128 * 32];
  int t = threadIdx.x;

  // XCD-aware swizzle: bid%8 selects the XCD (round-robin dispatch); give each XCD a
  // contiguous run of mt values with all NT column-siblings adjacent, so the A row-tile
  // stays hot in that XCD's private L2 across its 8 re-reads.
  int bidx = blockIdx.x;
  int nmt = (int)gridDim.x / NT;
  int mt, nt;
  if ((nmt & 7) == 0) {
    int xcd = bidx & 7, slot = bidx >> 3;
    nt = slot % NT;
    mt = (slot / NT) * 8 + xcd;
  } else {
    nt = bidx % NT;
    mt = bidx / NT;
  }
  int mbase = mt << 7, nbase = nt << 7;
  int lane = t & 63, wid = t >> 6;
  int wy = wid >> 1, wx = wid & 1;
  int lr = lane & 15, lk = (lane >> 4) << 3;

  // staging geometry: each 1024B wave-chunk = 16 rows x 32 f16 elems.
  // lane l covers row (chunk*16 + l/4), elems ((l&3)*8 .. +8). wave w stages chunks 2w, 2w+1.
  int crow = lane >> 2;
  int cel = (lane & 3) << 3;
  int c0 = wid << 1;

  f32x4 zero = {0.f, 0.f, 0.f, 0.f};
  f32x4 acc[4][4];
  for (int i = 0; i < 4; i++)
    for (int j = 0; j < 4; j++) acc[i][j] = zero;

  for (int k0 = 0; k0 < HDIM; k0 += 32) {
    for (int c = c0; c < c0 + 2; c++) {
      size_t ga = (size_t)(mbase + (c << 4) + crow) * lda + k0 + cel;
      size_t gb = (size_t)(nbase + (c << 4) + crow) * ldb + bkoff + k0 + cel;
      int ldso = c << 9;  // chunk * 512 ushorts = 1024 B
      gload16(Ahi + ga, &sA[0][ldso]);
      gload16(Bhi + gb, &sB[0][ldso]);
      if (SPLIT) {
        gload16(Alo + ga, &sA[1][ldso]);
        gload16(Blo + gb, &sB[1][ldso]);
      }
    }
    __syncthreads();  // drains vmcnt(0): all LDS-direct loads landed, all waves present
    f16x8 ah[4], bh[4], al[4], bl[4];
    for (int i = 0; i < 4; i++) {
      int ar = (wy << 6) + (i << 4) + lr;
      int br = (wx << 6) + (i << 4) + lr;
      ah[i] = *reinterpret_cast<const f16x8*>(&sA[0][ar * 32 + lk]);
      bh[i] = *reinterpret_cast<const f16x8*>(&sB[0][br * 32 + lk]);
      if (SPLIT) {
        al[i] = *reinterpret_cast<const f16x8*>(&sA[1][ar * 32 + lk]);
        bl[i] = *reinterpret_cast<const f16x8*>(&sB[1][br * 32 + lk]);
      }
    }
    for (int i = 0; i < 4; i++)
      for (int j = 0; j < 4; j++) {
        acc[i][j] = __builtin_amdgcn_mfma_f32_16x16x32_f16(ah[i], bh[j], acc[i][j], 0, 0, 0);
        if (SPLIT) {
          acc[i][j] = __builtin_amdgcn_mfma_f32_16x16x32_f16(ah[i], bl[j], acc[i][j], 0, 0, 0);
          acc[i][j] = __builtin_amdgcn_mfma_f32_16x16x32_f16(al[i], bh[j], acc[i][j], 0, 0, 0);
        }
      }
    __syncthreads();  // protect LDS reuse by next K-step's staging
  }

  int q = lane >> 4, cc = lane & 15;
  if (MODE == MODE_OUT) {
    for (int i = 0; i < 4; i++)
      for (int r = 0; r < 4; r++) {
        int grow = mbase + (wy << 6) + (i << 4) + (q << 2) + r;
        for (int j = 0; j < 4; j++) {
          int gcol = nbase + (wx << 6) + (j << 4) + cc;
          Dout[(size_t)grow * ldd + gcol] = acc[i][j][r];
        }
      }
  } else if (MODE == MODE_SIM) {
    for (int i = 0; i < 4; i++)
      for (int r = 0; r < 4; r++) {
        int grow = mbase + (wy << 6) + (i << 4) + (q << 2) + r;
        unsigned long long best = 0ull;
        for (int j = 0; j < 4; j++) {
          float vv = acc[i][j][r];
          unsigned vb = __float_as_uint(vv);
          vb = (vb & 0x80000000u) ? ~vb : (vb | 0x80000000u);
          unsigned idxn = (unsigned)(nbase + (wx << 6) + (j << 4) + cc);
          unsigned long long key = ((unsigned long long)vb << 32) | (unsigned)(~idxn);
          if (key > best) best = key;
        }
        for (int m = 1; m <= 8; m <<= 1) {
          unsigned long long o = shfl_xor_u64(best, m);
          if (o > best) best = o;
        }
        if (cc == 0) atomicMax(keys + grow, best);
      }
  } else {  // MODE_MAIN
    for (int i = 0; i < 4; i++)
      for (int r = 0; r < 4; r++) {
        int grow = mbase + (wy << 6) + (i << 4) + (q << 2) + r;
        unsigned idx = ~(unsigned)(keys[grow] & 0xFFFFFFFFull);
        idx &= 1023u;  // safety clamp; argmax always lands <1000
        const float* ap = aproj + (size_t)idx * NOUT;
        for (int j = 0; j < 4; j++) {
          int gcol = nbase + (wx << 6) + (j << 4) + cc;
          out[(size_t)grow * NOUT + gcol] = acc[i][j][r] + ap[gcol];
        }
      }
  }
}

extern "C" void kernel_launch(void* const* d_in, const int* in_sizes, int n_in,
                              void* d_out, int out_size, void* d_ws, size_t ws_size,
                              hipStream_t stream) {
  const float* features = (const float*)d_in[0];
  const float* anchors = (const float*)d_in[1];
  const float* Wout = (const float*)d_in[2];
  float* out = (float*)d_out;

  char* p = (char*)d_ws;
  size_t off = 0;
  auto alloc = [&](size_t b) {
    char* r = p + off;
    off += (b + 255) & ~(size_t)255;
    return r;
  };
  unsigned short* fh = (unsigned short*)alloc((size_t)N_ROWS * HDIM * 2);
  unsigned short* fl = (unsigned short*)alloc((size_t)N_ROWS * HDIM * 2);
  unsigned short* ash = (unsigned short*)alloc((size_t)CPAD * HDIM * 2);
  unsigned short* asl = (unsigned short*)alloc((size_t)CPAD * HDIM * 2);
  unsigned short* anh = (unsigned short*)alloc((size_t)CPAD * HDIM * 2);
  unsigned short* wt = (unsigned short*)alloc((size_t)NOUT * KK2 * 2);
  float* ap = (float*)alloc((size_t)CPAD * NOUT * 4);
  unsigned long long* keys = (unsigned long long*)alloc((size_t)N_ROWS * 8);
  if (off > ws_size) return;  // workspace too small; bench will show failure

  init_keys_kernel<<<N_ROWS / 256, 256, 0, stream>>>(keys);
  prep_anchors_kernel<<<CPAD, 256, 0, stream>>>(anchors, ash, asl, anh);
  fsplit_kernel<<<(N_ROWS * HDIM / 4) / 256, 256, 0, stream>>>(features, fh, fl);
  wtrans_kernel<<<512, 256, 0, stream>>>(Wout, wt);
  // anchor_proj = class_anchors @ W[0:1024,:]  -> ap [1024(pad) x 1024] fp32
  gemm_kernel<MODE_OUT><<<64, 256, 0, stream>>>(anh, nullptr, wt, nullptr,
                                                HDIM, KK2, 0, 8, ap, NOUT,
                                                nullptr, nullptr, nullptr);
  // sim + argmax (3-term fp16 split), result packed into keys
  gemm_kernel<MODE_SIM><<<2048, 256, 0, stream>>>(fh, fl, ash, asl,
                                                  HDIM, HDIM, 0, 8, nullptr, 0,
                                                  keys, nullptr, nullptr);
  // out = features @ W[1024:2048,:] + anchor_proj[idx]
  gemm_kernel<MODE_MAIN><<<2048, 256, 0, stream>>>(fh, nullptr, wt, nullptr,
                                                   HDIM, KK2, HDIM, 8, nullptr, 0,
                                                   keys, ap, out);
}

// Round 2
// 572.576 us; speedup vs baseline: 1.1812x; 1.0217x over previous
//
#include <hip/hip_runtime.h>

#define N_ROWS 32768
#define HDIM 1024
#define NCLS 1000
#define CPAD 1024
#define NOUT 1024
#define KK2 2048

typedef __attribute__((ext_vector_type(8))) unsigned short ushort8v;
typedef __attribute__((ext_vector_type(4))) unsigned short ushort4v;
typedef __attribute__((ext_vector_type(8))) _Float16 f16x8;
typedef __attribute__((ext_vector_type(4))) float f32x4;

__device__ inline unsigned short h_bits(_Float16 h) {
  union { _Float16 h; unsigned short u; } c; c.h = h; return c.u;
}

__device__ inline unsigned long long shfl_xor_u64(unsigned long long v, int m) {
  int lo = __shfl_xor((int)(unsigned)(v & 0xFFFFFFFFull), m, 64);
  int hi = __shfl_xor((int)(unsigned)(v >> 32), m, 64);
  return ((unsigned long long)(unsigned)hi << 32) | (unsigned)lo;
}

// async global -> LDS, 16B per lane. LDS dest is wave-uniform base + lane*16.
__device__ __forceinline__ void gload16(const void* g, void* l) {
  __builtin_amdgcn_global_load_lds(
      (__attribute__((address_space(1))) void*)g,
      (__attribute__((address_space(3))) void*)l, 16, 0, 0);
}

__global__ __launch_bounds__(256) void init_keys_kernel(unsigned long long* __restrict__ keys) {
  keys[(size_t)blockIdx.x * 256 + threadIdx.x] = 0ull;
}

// One block per (padded) anchor row: norm, scale by 1024/max(norm,eps), fp16 hi/lo split.
__global__ __launch_bounds__(256) void prep_anchors_kernel(
    const float* __restrict__ anchors, unsigned short* __restrict__ ash,
    unsigned short* __restrict__ asl, unsigned short* __restrict__ anh) {
  int c = blockIdx.x;
  int t = threadIdx.x;
  float v[4];
  float ss = 0.f;
  if (c < NCLS) {
    for (int i = 0; i < 4; i++) {
      v[i] = anchors[(size_t)c * HDIM + (i << 8) + t];
      ss += v[i] * v[i];
    }
  } else {
    v[0] = v[1] = v[2] = v[3] = 0.f;
  }
  for (int m = 1; m < 64; m <<= 1) ss += __shfl_xor(ss, m, 64);
  __shared__ float wsum[4];
  if ((t & 63) == 0) wsum[t >> 6] = ss;
  __syncthreads();
  float tot = wsum[0] + wsum[1] + wsum[2] + wsum[3];
  // scale by 1024 so the fp16 "lo" part stays clear of subnormals; argmax-invariant
  float scale = 1024.0f / fmaxf(sqrtf(tot), 1e-8f);
  for (int i = 0; i < 4; i++) {
    float x = v[i] * scale;
    _Float16 hi = (_Float16)x;
    float lo = x - (float)hi;
    size_t o = (size_t)c * HDIM + (i << 8) + t;
    ash[o] = h_bits(hi);
    asl[o] = h_bits((_Float16)lo);
    anh[o] = h_bits((_Float16)v[i]);
  }
}

// features fp32 -> fp16 hi + fp16 lo, vectorized
__global__ __launch_bounds__(256) void fsplit_kernel(const float* __restrict__ f,
    unsigned short* __restrict__ fh, unsigned short* __restrict__ fl) {
  size_t i = (size_t)blockIdx.x * 256 + threadIdx.x;
  float4 v = reinterpret_cast<const float4*>(f)[i];
  float xs[4] = {v.x, v.y, v.z, v.w};
  ushort4v h, l;
  for (int j = 0; j < 4; j++) {
    _Float16 hi = (_Float16)xs[j];
    float lo = xs[j] - (float)hi;
    h[j] = h_bits(hi);
    l[j] = h_bits((_Float16)lo);
  }
  reinterpret_cast<ushort4v*>(fh)[i] = h;
  reinterpret_cast<ushort4v*>(fl)[i] = l;
}

// W [2048,1024] fp32 row-major -> Wt [1024,2048] fp16 (k contiguous), via LDS transpose
__global__ __launch_bounds__(256) void wtrans_kernel(const float* __restrict__ W,
                                                     unsigned short* __restrict__ Wt) {
  __shared__ float tile[64][65];
  int kb = (blockIdx.x >> 4) << 6;  // 32 k-tiles
  int nb = (blockIdx.x & 15) << 6;  // 16 n-tiles
  int t = threadIdx.x;
  int tc = t & 63, tr = t >> 6;
  for (int i = 0; i < 16; i++) {
    int r = (i << 2) + tr;
    tile[r][tc] = W[(size_t)(kb + r) * NOUT + nb + tc];
  }
  __syncthreads();
  for (int i = 0; i < 16; i++) {
    int r = (i << 2) + tr;
    Wt[(size_t)(nb + r) * KK2 + kb + tc] = h_bits((_Float16)tile[tc][r]);
  }
}

enum { MODE_OUT = 0, MODE_SIM = 1, MODE_MAIN = 2 };

// C = A (M x K, k-contig) * B^T (rows of B are k-contig), 128x128 tile, 4 waves,
// 16x16x32 f16 MFMA. Staging via global_load_lds (width 16) into [128][32] LDS with an
// intra-row 16B XOR swizzle (phys_chunk = q ^ ((row>>1)&3)) -> ds_read_b128 is 2-way
// (free) instead of 8-way bank-conflicted. The swizzle permutes only within each 64B
// row, so the gload source keeps its coalesced 16-rows x 64B shape (rule: both-sides
// swizzle = inverse-permuted SOURCE + swizzled READ; LDS dest stays linear).
// MODE_SIM: 3-term hi/lo product + packed-key atomic argmax.
// MODE_MAIN: epilogue adds aproj[idx[row]].
template <int MODE>
__global__ __launch_bounds__(256) void gemm_kernel(
    const unsigned short* __restrict__ Ahi, const unsigned short* __restrict__ Alo,
    const unsigned short* __restrict__ Bhi, const unsigned short* __restrict__ Blo,
    int lda, int ldb, int bkoff, int NT,
    float* __restrict__ Dout, int ldd,
    unsigned long long* __restrict__ keys,
    const float* __restrict__ aproj,
    float* __restrict__ out) {
  constexpr bool SPLIT = (MODE == MODE_SIM);
  __shared__ unsigned short sA[SPLIT ? 2 : 1][128 * 32];
  __shared__ unsigned short sB[SPLIT ? 2 : 1][128 * 32];
  int t = threadIdx.x;

  // XCD-aware swizzle: bid%8 selects the XCD (round-robin dispatch); give each XCD a
  // contiguous run of mt values with all NT column-siblings adjacent, so the A row-tile
  // stays hot in that XCD's private L2 across its 8 re-reads.
  int bidx = blockIdx.x;
  int nmt = (int)gridDim.x / NT;
  int mt, nt;
  if ((nmt & 7) == 0) {
    int xcd = bidx & 7, slot = bidx >> 3;
    nt = slot % NT;
    mt = (slot / NT) * 8 + xcd;
  } else {
    nt = bidx % NT;
    mt = bidx / NT;
  }
  int mbase = mt << 7, nbase = nt << 7;
  int lane = t & 63, wid = t >> 6;
  int wy = wid >> 1, wx = wid & 1;
  int lr = lane & 15;
  // swizzled 16B-chunk for fragment reads: phys chunk = q ^ ((lr>>1)&3)
  int lk2 = (((lane >> 4) ^ ((lane >> 1) & 3)) << 3);

  // staging geometry: unit u (1KB) = 16 rows x 64B; lane l covers row u*16 + (l>>2),
  // physical 16B quad (l&3) which under the swizzle holds logical col chunk
  // (l&3) ^ ((l>>3)&3)  (independent of u since u*16 only touches row bits >=4).
  int crow = lane >> 2;
  int celsw = (((lane & 3) ^ ((lane >> 3) & 3)) << 3);
  int c0 = wid << 1;

  // hoisted staging pointers (per-thread); k0 is the only loop-varying term
  const unsigned short* pa0 = Ahi + (size_t)(mbase + (c0 << 4) + crow) * lda + celsw;
  const unsigned short* pa1 = pa0 + (size_t)16 * lda;
  const unsigned short* pb0 = Bhi + (size_t)(nbase + (c0 << 4) + crow) * ldb + bkoff + celsw;
  const unsigned short* pb1 = pb0 + (size_t)16 * ldb;
  const unsigned short* qa0 = nullptr; const unsigned short* qa1 = nullptr;
  const unsigned short* qb0 = nullptr; const unsigned short* qb1 = nullptr;
  if constexpr (SPLIT) {
    qa0 = Alo + (pa0 - Ahi); qa1 = Alo + (pa1 - Ahi);
    qb0 = Blo + (pb0 - Bhi); qb1 = Blo + (pb1 - Bhi);
  }
  unsigned short* dA0 = &sA[0][(size_t)c0 << 9];
  unsigned short* dA1 = &sA[0][(size_t)(c0 + 1) << 9];
  unsigned short* dB0 = &sB[0][(size_t)c0 << 9];
  unsigned short* dB1 = &sB[0][(size_t)(c0 + 1) << 9];
  unsigned short* eA0 = nullptr; unsigned short* eA1 = nullptr;
  unsigned short* eB0 = nullptr; unsigned short* eB1 = nullptr;
  if constexpr (SPLIT) {
    eA0 = &sA[1][(size_t)c0 << 9]; eA1 = &sA[1][(size_t)(c0 + 1) << 9];
    eB0 = &sB[1][(size_t)c0 << 9]; eB1 = &sB[1][(size_t)(c0 + 1) << 9];
  }

  f32x4 zero = {0.f, 0.f, 0.f, 0.f};
  f32x4 acc[4][4];
  for (int i = 0; i < 4; i++)
    for (int j = 0; j < 4; j++) acc[i][j] = zero;

  for (int k0 = 0; k0 < HDIM; k0 += 32) {
    gload16(pa0 + k0, dA0);
    gload16(pa1 + k0, dA1);
    gload16(pb0 + k0, dB0);
    gload16(pb1 + k0, dB1);
    if constexpr (SPLIT) {
      gload16(qa0 + k0, eA0);
      gload16(qa1 + k0, eA1);
      gload16(qb0 + k0, eB0);
      gload16(qb1 + k0, eB1);
    }
    __syncthreads();  // drains vmcnt(0): all LDS-direct loads landed, all waves present
    f16x8 ah[4], bh[4], al[4], bl[4];
    for (int i = 0; i < 4; i++) {
      int ar = (wy << 6) + (i << 4) + lr;
      int br = (wx << 6) + (i << 4) + lr;
      ah[i] = *reinterpret_cast<const f16x8*>(&sA[0][ar * 32 + lk2]);
      bh[i] = *reinterpret_cast<const f16x8*>(&sB[0][br * 32 + lk2]);
      if constexpr (SPLIT) {
        al[i] = *reinterpret_cast<const f16x8*>(&sA[1][ar * 32 + lk2]);
        bl[i] = *reinterpret_cast<const f16x8*>(&sB[1][br * 32 + lk2]);
      }
    }
    for (int i = 0; i < 4; i++)
      for (int j = 0; j < 4; j++) {
        acc[i][j] = __builtin_amdgcn_mfma_f32_16x16x32_f16(ah[i], bh[j], acc[i][j], 0, 0, 0);
        if constexpr (SPLIT) {
          acc[i][j] = __builtin_amdgcn_mfma_f32_16x16x32_f16(ah[i], bl[j], acc[i][j], 0, 0, 0);
          acc[i][j] = __builtin_amdgcn_mfma_f32_16x16x32_f16(al[i], bh[j], acc[i][j], 0, 0, 0);
        }
      }
    __syncthreads();  // protect LDS reuse by next K-step's staging
  }

  int q = lane >> 4, cc = lane & 15;
  if (MODE == MODE_OUT) {
    for (int i = 0; i < 4; i++)
      for (int r = 0; r < 4; r++) {
        int grow = mbase + (wy << 6) + (i << 4) + (q << 2) + r;
        for (int j = 0; j < 4; j++) {
          int gcol = nbase + (wx << 6) + (j << 4) + cc;
          Dout[(size_t)grow * ldd + gcol] = acc[i][j][r];
        }
      }
  } else if (MODE == MODE_SIM) {
    for (int i = 0; i < 4; i++)
      for (int r = 0; r < 4; r++) {
        int grow = mbase + (wy << 6) + (i << 4) + (q << 2) + r;
        unsigned long long best = 0ull;
        for (int j = 0; j < 4; j++) {
          float vv = acc[i][j][r];
          unsigned vb = __float_as_uint(vv);
          vb = (vb & 0x80000000u) ? ~vb : (vb | 0x80000000u);
          unsigned idxn = (unsigned)(nbase + (wx << 6) + (j << 4) + cc);
          unsigned long long key = ((unsigned long long)vb << 32) | (unsigned)(~idxn);
          if (key > best) best = key;
        }
        for (int m = 1; m <= 8; m <<= 1) {
          unsigned long long o = shfl_xor_u64(best, m);
          if (o > best) best = o;
        }
        if (cc == 0) atomicMax(keys + grow, best);
      }
  } else {  // MODE_MAIN
    for (int i = 0; i < 4; i++)
      for (int r = 0; r < 4; r++) {
        int grow = mbase + (wy << 6) + (i << 4) + (q << 2) + r;
        unsigned idx = ~(unsigned)(keys[grow] & 0xFFFFFFFFull);
        idx &= 1023u;  // safety clamp; argmax always lands <1000
        const float* ap = aproj + (size_t)idx * NOUT;
        for (int j = 0; j < 4; j++) {
          int gcol = nbase + (wx << 6) + (j << 4) + cc;
          out[(size_t)grow * NOUT + gcol] = acc[i][j][r] + ap[gcol];
        }
      }
  }
}

extern "C" void kernel_launch(void* const* d_in, const int* in_sizes, int n_in,
                              void* d_out, int out_size, void* d_ws, size_t ws_size,
                              hipStream_t stream) {
  const float* features = (const float*)d_in[0];
  const float* anchors = (const float*)d_in[1];
  const float* Wout = (const float*)d_in[2];
  float* out = (float*)d_out;

  char* p = (char*)d_ws;
  size_t off = 0;
  auto alloc = [&](size_t b) {
    char* r = p + off;
    off += (b + 255) & ~(size_t)255;
    return r;
  };
  unsigned short* fh = (unsigned short*)alloc((size_t)N_ROWS * HDIM * 2);
  unsigned short* fl = (unsigned short*)alloc((size_t)N_ROWS * HDIM * 2);
  unsigned short* ash = (unsigned short*)alloc((size_t)CPAD * HDIM * 2);
  unsigned short* asl = (unsigned short*)alloc((size_t)CPAD * HDIM * 2);
  unsigned short* anh = (unsigned short*)alloc((size_t)CPAD * HDIM * 2);
  unsigned short* wt = (unsigned short*)alloc((size_t)NOUT * KK2 * 2);
  float* ap = (float*)alloc((size_t)CPAD * NOUT * 4);
  unsigned long long* keys = (unsigned long long*)alloc((size_t)N_ROWS * 8);
  if (off > ws_size) return;  // workspace too small; bench will show failure

  init_keys_kernel<<<N_ROWS / 256, 256, 0, stream>>>(keys);
  prep_anchors_kernel<<<CPAD, 256, 0, stream>>>(anchors, ash, asl, anh);
  fsplit_kernel<<<(N_ROWS * HDIM / 4) / 256, 256, 0, stream>>>(features, fh, fl);
  wtrans_kernel<<<512, 256, 0, stream>>>(Wout, wt);
  // anchor_proj = class_anchors @ W[0:1024,:]  -> ap [1024(pad) x 1024] fp32
  gemm_kernel<MODE_OUT><<<64, 256, 0, stream>>>(anh, nullptr, wt, nullptr,
                                                HDIM, KK2, 0, 8, ap, NOUT,
                                                nullptr, nullptr, nullptr);
  // sim + argmax (3-term fp16 split), result packed into keys
  gemm_kernel<MODE_SIM><<<2048, 256, 0, stream>>>(fh, fl, ash, asl,
                                                  HDIM, HDIM, 0, 8, nullptr, 0,
                                                  keys, nullptr, nullptr);
  // out = features @ W[1024:2048,:] + anchor_proj[idx]
  gemm_kernel<MODE_MAIN><<<2048, 256, 0, stream>>>(fh, nullptr, wt, nullptr,
                                                   HDIM, KK2, HDIM, 8, nullptr, 0,
                                                   keys, ap, out);
}

// Round 3
// 529.652 us; speedup vs baseline: 1.2769x; 1.0810x over previous
//
#include <hip/hip_runtime.h>

#define N_ROWS 32768
#define HDIM 1024
#define NCLS 1000
#define CPAD 1024
#define NOUT 1024
#define KK2 2048

typedef __attribute__((ext_vector_type(8))) unsigned short ushort8v;
typedef __attribute__((ext_vector_type(4))) unsigned short ushort4v;
typedef __attribute__((ext_vector_type(8))) _Float16 f16x8;
typedef __attribute__((ext_vector_type(4))) float f32x4;

#define WAITVM(n) asm volatile("s_waitcnt vmcnt(" #n ")" ::: "memory")
#define LGKM0() do { asm volatile("s_waitcnt lgkmcnt(0)" ::: "memory"); \
                     __builtin_amdgcn_sched_barrier(0); } while (0)
#define BAR() __builtin_amdgcn_s_barrier()

__device__ inline unsigned short h_bits(_Float16 h) {
  union { _Float16 h; unsigned short u; } c; c.h = h; return c.u;
}

__device__ inline unsigned long long shfl_xor_u64(unsigned long long v, int m) {
  int lo = __shfl_xor((int)(unsigned)(v & 0xFFFFFFFFull), m, 64);
  int hi = __shfl_xor((int)(unsigned)(v >> 32), m, 64);
  return ((unsigned long long)(unsigned)hi << 32) | (unsigned)lo;
}

// async global -> LDS, 16B per lane. LDS dest is wave-uniform base + lane*16.
__device__ __forceinline__ void gload16(const void* g, void* l) {
  __builtin_amdgcn_global_load_lds(
      (__attribute__((address_space(1))) void*)g,
      (__attribute__((address_space(3))) void*)l, 16, 0, 0);
}

__global__ __launch_bounds__(256) void init_keys_kernel(unsigned long long* __restrict__ keys) {
  keys[(size_t)blockIdx.x * 256 + threadIdx.x] = 0ull;
}

// One block per (padded) anchor row: norm, scale by 1024/max(norm,eps), fp16 hi/lo split.
__global__ __launch_bounds__(256) void prep_anchors_kernel(
    const float* __restrict__ anchors, unsigned short* __restrict__ ash,
    unsigned short* __restrict__ asl, unsigned short* __restrict__ anh) {
  int c = blockIdx.x;
  int t = threadIdx.x;
  float v[4];
  float ss = 0.f;
  if (c < NCLS) {
    for (int i = 0; i < 4; i++) {
      v[i] = anchors[(size_t)c * HDIM + (i << 8) + t];
      ss += v[i] * v[i];
    }
  } else {
    v[0] = v[1] = v[2] = v[3] = 0.f;
  }
  for (int m = 1; m < 64; m <<= 1) ss += __shfl_xor(ss, m, 64);
  __shared__ float wsum[4];
  if ((t & 63) == 0) wsum[t >> 6] = ss;
  __syncthreads();
  float tot = wsum[0] + wsum[1] + wsum[2] + wsum[3];
  float scale = 1024.0f / fmaxf(sqrtf(tot), 1e-8f);
  for (int i = 0; i < 4; i++) {
    float x = v[i] * scale;
    _Float16 hi = (_Float16)x;
    float lo = x - (float)hi;
    size_t o = (size_t)c * HDIM + (i << 8) + t;
    ash[o] = h_bits(hi);
    asl[o] = h_bits((_Float16)lo);
    anh[o] = h_bits((_Float16)v[i]);
  }
}

// features fp32 -> fp16 hi + fp16 lo, vectorized
__global__ __launch_bounds__(256) void fsplit_kernel(const float* __restrict__ f,
    unsigned short* __restrict__ fh, unsigned short* __restrict__ fl) {
  size_t i = (size_t)blockIdx.x * 256 + threadIdx.x;
  float4 v = reinterpret_cast<const float4*>(f)[i];
  float xs[4] = {v.x, v.y, v.z, v.w};
  ushort4v h, l;
  for (int j = 0; j < 4; j++) {
    _Float16 hi = (_Float16)xs[j];
    float lo = xs[j] - (float)hi;
    h[j] = h_bits(hi);
    l[j] = h_bits((_Float16)lo);
  }
  reinterpret_cast<ushort4v*>(fh)[i] = h;
  reinterpret_cast<ushort4v*>(fl)[i] = l;
}

// W [2048,1024] fp32 row-major -> Wt [1024,2048] fp16 (k contiguous), via LDS transpose
__global__ __launch_bounds__(256) void wtrans_kernel(const float* __restrict__ W,
                                                     unsigned short* __restrict__ Wt) {
  __shared__ float tile[64][65];
  int kb = (blockIdx.x >> 4) << 6;
  int nb = (blockIdx.x & 15) << 6;
  int t = threadIdx.x;
  int tc = t & 63, tr = t >> 6;
  for (int i = 0; i < 16; i++) {
    int r = (i << 2) + tr;
    tile[r][tc] = W[(size_t)(kb + r) * NOUT + nb + tc];
  }
  __syncthreads();
  for (int i = 0; i < 16; i++) {
    int r = (i << 2) + tr;
    Wt[(size_t)(nb + r) * KK2 + kb + tc] = h_bits((_Float16)tile[tc][r]);
  }
}

enum { MODE_OUT = 0, MODE_SIM = 1, MODE_MAIN = 2 };

// ---------------- old verified 128x128 4-wave kernel (kept for MODE_OUT: tiny grid) -------------
template <int MODE>
__global__ __launch_bounds__(256) void gemm_kernel(
    const unsigned short* __restrict__ Ahi, const unsigned short* __restrict__ Alo,
    const unsigned short* __restrict__ Bhi, const unsigned short* __restrict__ Blo,
    int lda, int ldb, int bkoff, int NT,
    float* __restrict__ Dout, int ldd,
    unsigned long long* __restrict__ keys,
    const float* __restrict__ aproj,
    float* __restrict__ out) {
  constexpr bool SPLIT = (MODE == MODE_SIM);
  __shared__ unsigned short sA[SPLIT ? 2 : 1][128 * 32];
  __shared__ unsigned short sB[SPLIT ? 2 : 1][128 * 32];
  int t = threadIdx.x;
  int bidx = blockIdx.x;
  int nmt = (int)gridDim.x / NT;
  int mt, nt;
  if ((nmt & 7) == 0) {
    int xcd = bidx & 7, slot = bidx >> 3;
    nt = slot % NT;
    mt = (slot / NT) * 8 + xcd;
  } else {
    nt = bidx % NT;
    mt = bidx / NT;
  }
  int mbase = mt << 7, nbase = nt << 7;
  int lane = t & 63, wid = t >> 6;
  int wy = wid >> 1, wx = wid & 1;
  int lr = lane & 15;
  int lk2 = (((lane >> 4) ^ ((lane >> 1) & 3)) << 3);
  int crow = lane >> 2;
  int celsw = (((lane & 3) ^ ((lane >> 3) & 3)) << 3);
  int c0 = wid << 1;

  const unsigned short* pa0 = Ahi + (size_t)(mbase + (c0 << 4) + crow) * lda + celsw;
  const unsigned short* pa1 = pa0 + (size_t)16 * lda;
  const unsigned short* pb0 = Bhi + (size_t)(nbase + (c0 << 4) + crow) * ldb + bkoff + celsw;
  const unsigned short* pb1 = pb0 + (size_t)16 * ldb;
  unsigned short* dA0 = &sA[0][(size_t)c0 << 9];
  unsigned short* dA1 = &sA[0][(size_t)(c0 + 1) << 9];
  unsigned short* dB0 = &sB[0][(size_t)c0 << 9];
  unsigned short* dB1 = &sB[0][(size_t)(c0 + 1) << 9];

  f32x4 zero = {0.f, 0.f, 0.f, 0.f};
  f32x4 acc[4][4];
  for (int i = 0; i < 4; i++)
    for (int j = 0; j < 4; j++) acc[i][j] = zero;

  for (int k0 = 0; k0 < HDIM; k0 += 32) {
    gload16(pa0 + k0, dA0);
    gload16(pa1 + k0, dA1);
    gload16(pb0 + k0, dB0);
    gload16(pb1 + k0, dB1);
    __syncthreads();
    f16x8 ah[4], bh[4];
    for (int i = 0; i < 4; i++) {
      int ar = (wy << 6) + (i << 4) + lr;
      int br = (wx << 6) + (i << 4) + lr;
      ah[i] = *reinterpret_cast<const f16x8*>(&sA[0][ar * 32 + lk2]);
      bh[i] = *reinterpret_cast<const f16x8*>(&sB[0][br * 32 + lk2]);
    }
    for (int i = 0; i < 4; i++)
      for (int j = 0; j < 4; j++)
        acc[i][j] = __builtin_amdgcn_mfma_f32_16x16x32_f16(ah[i], bh[j], acc[i][j], 0, 0, 0);
    __syncthreads();
  }

  int q = lane >> 4, cc = lane & 15;
  for (int i = 0; i < 4; i++)
    for (int r = 0; r < 4; r++) {
      int grow = mbase + (wy << 6) + (i << 4) + (q << 2) + r;
      for (int j = 0; j < 4; j++) {
        int gcol = nbase + (wx << 6) + (j << 4) + cc;
        Dout[(size_t)grow * ldd + gcol] = acc[i][j][r];
      }
    }
}

// ---------------- new 256x256 8-wave pipelined kernel (SIM / MAIN) ----------------
// Double-buffered LDS, counted vmcnt (never 0 in steady state), raw s_barrier,
// setprio around MFMA clusters, T2 intra-row swizzle (verified: conflicts == 0).
// Per tile stage order: Ah,Ah,Bh,Bh[,Bl,Bl,Al,Al]; phases hh / h*lo / lo*h.
template <int MODE>
__global__ __launch_bounds__(512, 2) void gemm256_kernel(
    const unsigned short* __restrict__ Ahi, const unsigned short* __restrict__ Alo,
    const unsigned short* __restrict__ Bhi, const unsigned short* __restrict__ Blo,
    int lda, int ldb, int bkoff, int NT,
    unsigned long long* __restrict__ keys,
    const float* __restrict__ aproj,
    float* __restrict__ out) {
  constexpr bool SPLIT = (MODE == MODE_SIM);
  // flat LDS, ushort units. per-matrix-per-buf = 256 rows x 32 elems = 8192.
  __shared__ unsigned short lds[SPLIT ? 65536 : 32768];
  constexpr int AHO = 0;
  constexpr int BHO = SPLIT ? 32768 : 16384;
  constexpr int ALO_ = SPLIT ? 16384 : 0;
  constexpr int BLO_ = SPLIT ? 49152 : 0;

  int t = threadIdx.x;
  int bidx = blockIdx.x;
  int nmt = (int)gridDim.x / NT;
  int mt, nt;
  if ((nmt & 7) == 0) {
    int xcd = bidx & 7, slot = bidx >> 3;
    nt = slot % NT;
    mt = (slot / NT) * 8 + xcd;
  } else {
    nt = bidx % NT;
    mt = bidx / NT;
  }
  int mbase = mt << 8, nbase = nt << 8;
  int lane = t & 63, wid = t >> 6;       // 8 waves
  int wy = wid >> 2, wx = wid & 3;       // 2 x 4 wave grid; wave tile 128 x 64
  int lr = lane & 15;
  int lk2 = (((lane >> 4) ^ ((lane >> 1) & 3)) << 3);  // swizzled read chunk

  // staging: 8KB sweep = 512 threads x 16B = 128 rows x 64B. thread covers
  // row wid*16 + (lane>>2), logical col chunk (lane&3)^((lane>>3)&3).
  int srow = (wid << 4) + (lane >> 2);
  int scol = (((lane & 3) ^ ((lane >> 3) & 3)) << 3);
  int wdst = wid << 9;  // wave's 1KB sub-block within an 8KB sweep (ushorts)

  const unsigned short* gAh = Ahi + (size_t)(mbase + srow) * lda + scol;
  const unsigned short* gBh = Bhi + (size_t)(nbase + srow) * ldb + bkoff + scol;
  const unsigned short* gAl = nullptr;
  const unsigned short* gBl = nullptr;
  if constexpr (SPLIT) {
    gAl = Alo + (gAh - Ahi);
    gBl = Blo + (gBh - Bhi);
  }
  const size_t a128 = (size_t)128 * lda, b128 = (size_t)128 * ldb;

  auto STAGE = [&](int k0v, int cb) {
    int co = cb << 13;  // cb * 8192
    gload16(gAh + k0v, &lds[AHO + co + wdst]);
    gload16(gAh + a128 + k0v, &lds[AHO + co + 4096 + wdst]);
    gload16(gBh + k0v, &lds[BHO + co + wdst]);
    gload16(gBh + b128 + k0v, &lds[BHO + co + 4096 + wdst]);
    if constexpr (SPLIT) {
      gload16(gBl + k0v, &lds[BLO_ + co + wdst]);
      gload16(gBl + b128 + k0v, &lds[BLO_ + co + 4096 + wdst]);
      gload16(gAl + k0v, &lds[ALO_ + co + wdst]);
      gload16(gAl + a128 + k0v, &lds[ALO_ + co + 4096 + wdst]);
    }
  };

  // fragment read bases (ushort offsets within a matrix-buf)
  int arowb = (((wy << 7) + lr) << 5) + lk2;  // + i*512
  int browb = (((wx << 6) + lr) << 5) + lk2;  // + j*512

  f32x4 zero = {0.f, 0.f, 0.f, 0.f};
  f32x4 acc[8][4];
#pragma unroll
  for (int i = 0; i < 8; i++)
#pragma unroll
    for (int j = 0; j < 4; j++) acc[i][j] = zero;

  STAGE(0, 0);
  STAGE(32, 1);

  for (int tt = 0; tt < 32; ++tt) {
    int cb = tt & 1;
    int co = cb << 13;
    // ---- phase HH: needs Ah,Bh(tt); issued-after = 4 (+8 next tile) ----
    if constexpr (SPLIT) {
      if (tt < 31) { WAITVM(12); } else { WAITVM(4); }
    } else {
      if (tt < 31) { WAITVM(4); } else { WAITVM(0); }
    }
    BAR();
    f16x8 ah[8], bh[4];
#pragma unroll
    for (int i = 0; i < 8; i++)
      ah[i] = *reinterpret_cast<const f16x8*>(&lds[AHO + co + arowb + (i << 9)]);
#pragma unroll
    for (int j = 0; j < 4; j++)
      bh[j] = *reinterpret_cast<const f16x8*>(&lds[BHO + co + browb + (j << 9)]);
    LGKM0();
    __builtin_amdgcn_s_setprio(1);
#pragma unroll
    for (int i = 0; i < 8; i++)
#pragma unroll
      for (int j = 0; j < 4; j++)
        acc[i][j] = __builtin_amdgcn_mfma_f32_16x16x32_f16(ah[i], bh[j], acc[i][j], 0, 0, 0);
    __builtin_amdgcn_s_setprio(0);
    if constexpr (SPLIT) {
      // ---- phase HL: needs Bl(tt); issued-after = 2 (+8) ----
      if (tt < 31) { WAITVM(10); } else { WAITVM(2); }
      BAR();
      f16x8 bl[4];
#pragma unroll
      for (int j = 0; j < 4; j++)
        bl[j] = *reinterpret_cast<const f16x8*>(&lds[BLO_ + co + browb + (j << 9)]);
      LGKM0();
      __builtin_amdgcn_s_setprio(1);
#pragma unroll
      for (int i = 0; i < 8; i++)
#pragma unroll
        for (int j = 0; j < 4; j++)
          acc[i][j] = __builtin_amdgcn_mfma_f32_16x16x32_f16(ah[i], bl[j], acc[i][j], 0, 0, 0);
      __builtin_amdgcn_s_setprio(0);
      // ---- phase LH: needs Al(tt); issued-after = 0 (+8) ----
      if (tt < 31) { WAITVM(8); } else { WAITVM(0); }
      BAR();
      f16x8 al[8];
#pragma unroll
      for (int i = 0; i < 8; i++)
        al[i] = *reinterpret_cast<const f16x8*>(&lds[ALO_ + co + arowb + (i << 9)]);
      LGKM0();
      __builtin_amdgcn_s_setprio(1);
#pragma unroll
      for (int i = 0; i < 8; i++)
#pragma unroll
        for (int j = 0; j < 4; j++)
          acc[i][j] = __builtin_amdgcn_mfma_f32_16x16x32_f16(al[i], bh[j], acc[i][j], 0, 0, 0);
      __builtin_amdgcn_s_setprio(0);
    }
    BAR();  // all waves done reading buf cb -> safe to overwrite with tile tt+2
    if (tt < 30) STAGE((tt + 2) << 5, cb);
  }

  int q = lane >> 4, cc = lane & 15;
  int wrowb = mbase + (wy << 7), wcolb = nbase + (wx << 6);
  if constexpr (MODE == MODE_SIM) {
#pragma unroll
    for (int i = 0; i < 8; i++)
#pragma unroll
      for (int r = 0; r < 4; r++) {
        int grow = wrowb + (i << 4) + (q << 2) + r;
        unsigned long long best = 0ull;
#pragma unroll
        for (int j = 0; j < 4; j++) {
          float vv = acc[i][j][r];
          unsigned vb = __float_as_uint(vv);
          vb = (vb & 0x80000000u) ? ~vb : (vb | 0x80000000u);
          unsigned idxn = (unsigned)(wcolb + (j << 4) + cc);
          unsigned long long key = ((unsigned long long)vb << 32) | (unsigned)(~idxn);
          if (key > best) best = key;
        }
        for (int m = 1; m <= 8; m <<= 1) {
          unsigned long long o = shfl_xor_u64(best, m);
          if (o > best) best = o;
        }
        if (cc == 0) atomicMax(keys + grow, best);
      }
  } else {  // MODE_MAIN
#pragma unroll
    for (int i = 0; i < 8; i++)
#pragma unroll
      for (int r = 0; r < 4; r++) {
        int grow = wrowb + (i << 4) + (q << 2) + r;
        unsigned idx = ~(unsigned)(keys[grow] & 0xFFFFFFFFull);
        idx &= 1023u;
        const float* ap = aproj + (size_t)idx * NOUT;
#pragma unroll
        for (int j = 0; j < 4; j++) {
          int gcol = wcolb + (j << 4) + cc;
          out[(size_t)grow * NOUT + gcol] = acc[i][j][r] + ap[gcol];
        }
      }
  }
}

extern "C" void kernel_launch(void* const* d_in, const int* in_sizes, int n_in,
                              void* d_out, int out_size, void* d_ws, size_t ws_size,
                              hipStream_t stream) {
  const float* features = (const float*)d_in[0];
  const float* anchors = (const float*)d_in[1];
  const float* Wout = (const float*)d_in[2];
  float* out = (float*)d_out;

  char* p = (char*)d_ws;
  size_t off = 0;
  auto alloc = [&](size_t b) {
    char* r = p + off;
    off += (b + 255) & ~(size_t)255;
    return r;
  };
  unsigned short* fh = (unsigned short*)alloc((size_t)N_ROWS * HDIM * 2);
  unsigned short* fl = (unsigned short*)alloc((size_t)N_ROWS * HDIM * 2);
  unsigned short* ash = (unsigned short*)alloc((size_t)CPAD * HDIM * 2);
  unsigned short* asl = (unsigned short*)alloc((size_t)CPAD * HDIM * 2);
  unsigned short* anh = (unsigned short*)alloc((size_t)CPAD * HDIM * 2);
  unsigned short* wt = (unsigned short*)alloc((size_t)NOUT * KK2 * 2);
  float* ap = (float*)alloc((size_t)CPAD * NOUT * 4);
  unsigned long long* keys = (unsigned long long*)alloc((size_t)N_ROWS * 8);
  if (off > ws_size) return;

  init_keys_kernel<<<N_ROWS / 256, 256, 0, stream>>>(keys);
  prep_anchors_kernel<<<CPAD, 256, 0, stream>>>(anchors, ash, asl, anh);
  fsplit_kernel<<<(N_ROWS * HDIM / 4) / 256, 256, 0, stream>>>(features, fh, fl);
  wtrans_kernel<<<512, 256, 0, stream>>>(Wout, wt);
  // anchor_proj = class_anchors @ W[0:1024,:] -> ap (old verified 128^2 kernel; small grid)
  gemm_kernel<MODE_OUT><<<64, 256, 0, stream>>>(anh, nullptr, wt, nullptr,
                                                HDIM, KK2, 0, 8, ap, NOUT,
                                                nullptr, nullptr, nullptr);
  // sim + argmax (3-term fp16 split): 256^2 pipelined
  gemm256_kernel<MODE_SIM><<<512, 512, 0, stream>>>(fh, fl, ash, asl,
                                                    HDIM, HDIM, 0, 4,
                                                    keys, nullptr, nullptr);
  // out = features @ W[1024:2048,:] + anchor_proj[idx]: 256^2 pipelined
  gemm256_kernel<MODE_MAIN><<<512, 512, 0, stream>>>(fh, nullptr, wt, nullptr,
                                                     HDIM, KK2, HDIM, 4,
                                                     keys, ap, out);
}

// Round 4
// 529.109 us; speedup vs baseline: 1.2782x; 1.0010x over previous
//
#include <hip/hip_runtime.h>

#define N_ROWS 32768
#define HDIM 1024
#define NCLS 1000
#define CPAD 1024
#define NOUT 1024
#define KK2 2048

typedef __attribute__((ext_vector_type(8))) unsigned short ushort8v;
typedef __attribute__((ext_vector_type(4))) unsigned short ushort4v;
typedef __attribute__((ext_vector_type(8))) _Float16 f16x8;
typedef __attribute__((ext_vector_type(4))) float f32x4;

#define WAITVM(n) asm volatile("s_waitcnt vmcnt(" #n ")" ::: "memory")
#define LGKM(n) do { asm volatile("s_waitcnt lgkmcnt(" #n ")" ::: "memory"); \
                     __builtin_amdgcn_sched_barrier(0); } while (0)
#define BAR() __builtin_amdgcn_s_barrier()
#define SCHED0() __builtin_amdgcn_sched_barrier(0)

__device__ inline unsigned short h_bits(_Float16 h) {
  union { _Float16 h; unsigned short u; } c; c.h = h; return c.u;
}

__device__ inline unsigned long long shfl_xor_u64(unsigned long long v, int m) {
  int lo = __shfl_xor((int)(unsigned)(v & 0xFFFFFFFFull), m, 64);
  int hi = __shfl_xor((int)(unsigned)(v >> 32), m, 64);
  return ((unsigned long long)(unsigned)hi << 32) | (unsigned)lo;
}

// async global -> LDS, 16B per lane. LDS dest is wave-uniform base + lane*16.
__device__ __forceinline__ void gload16(const void* g, void* l) {
  __builtin_amdgcn_global_load_lds(
      (__attribute__((address_space(1))) void*)g,
      (__attribute__((address_space(3))) void*)l, 16, 0, 0);
}

__global__ __launch_bounds__(256) void init_keys_kernel(unsigned long long* __restrict__ keys) {
  keys[(size_t)blockIdx.x * 256 + threadIdx.x] = 0ull;
}

// One block per (padded) anchor row: norm, scale by 1024/max(norm,eps), fp16 hi/lo split.
__global__ __launch_bounds__(256) void prep_anchors_kernel(
    const float* __restrict__ anchors, unsigned short* __restrict__ ash,
    unsigned short* __restrict__ asl, unsigned short* __restrict__ anh) {
  int c = blockIdx.x;
  int t = threadIdx.x;
  float v[4];
  float ss = 0.f;
  if (c < NCLS) {
    for (int i = 0; i < 4; i++) {
      v[i] = anchors[(size_t)c * HDIM + (i << 8) + t];
      ss += v[i] * v[i];
    }
  } else {
    v[0] = v[1] = v[2] = v[3] = 0.f;
  }
  for (int m = 1; m < 64; m <<= 1) ss += __shfl_xor(ss, m, 64);
  __shared__ float wsum[4];
  if ((t & 63) == 0) wsum[t >> 6] = ss;
  __syncthreads();
  float tot = wsum[0] + wsum[1] + wsum[2] + wsum[3];
  float scale = 1024.0f / fmaxf(sqrtf(tot), 1e-8f);
  for (int i = 0; i < 4; i++) {
    float x = v[i] * scale;
    _Float16 hi = (_Float16)x;
    float lo = x - (float)hi;
    size_t o = (size_t)c * HDIM + (i << 8) + t;
    ash[o] = h_bits(hi);
    asl[o] = h_bits((_Float16)lo);
    anh[o] = h_bits((_Float16)v[i]);
  }
}

// features fp32 -> fp16 hi + fp16 lo, vectorized
__global__ __launch_bounds__(256) void fsplit_kernel(const float* __restrict__ f,
    unsigned short* __restrict__ fh, unsigned short* __restrict__ fl) {
  size_t i = (size_t)blockIdx.x * 256 + threadIdx.x;
  float4 v = reinterpret_cast<const float4*>(f)[i];
  float xs[4] = {v.x, v.y, v.z, v.w};
  ushort4v h, l;
  for (int j = 0; j < 4; j++) {
    _Float16 hi = (_Float16)xs[j];
    float lo = xs[j] - (float)hi;
    h[j] = h_bits(hi);
    l[j] = h_bits((_Float16)lo);
  }
  reinterpret_cast<ushort4v*>(fh)[i] = h;
  reinterpret_cast<ushort4v*>(fl)[i] = l;
}

// W [2048,1024] fp32 row-major -> Wt [1024,2048] fp16 (k contiguous), via LDS transpose
__global__ __launch_bounds__(256) void wtrans_kernel(const float* __restrict__ W,
                                                     unsigned short* __restrict__ Wt) {
  __shared__ float tile[64][65];
  int kb = (blockIdx.x >> 4) << 6;
  int nb = (blockIdx.x & 15) << 6;
  int t = threadIdx.x;
  int tc = t & 63, tr = t >> 6;
  for (int i = 0; i < 16; i++) {
    int r = (i << 2) + tr;
    tile[r][tc] = W[(size_t)(kb + r) * NOUT + nb + tc];
  }
  __syncthreads();
  for (int i = 0; i < 16; i++) {
    int r = (i << 2) + tr;
    Wt[(size_t)(nb + r) * KK2 + kb + tc] = h_bits((_Float16)tile[tc][r]);
  }
}

// ---------------- 128x128 4-wave kernel (kept for anchor_proj: tiny grid) ----------------
__global__ __launch_bounds__(256) void gemm_out_kernel(
    const unsigned short* __restrict__ Ahi, const unsigned short* __restrict__ Bhi,
    int lda, int ldb, int bkoff, int NT, float* __restrict__ Dout, int ldd) {
  __shared__ unsigned short sA[128 * 32];
  __shared__ unsigned short sB[128 * 32];
  int t = threadIdx.x;
  int bidx = blockIdx.x;
  int nt = bidx % NT, mt = bidx / NT;
  int mbase = mt << 7, nbase = nt << 7;
  int lane = t & 63, wid = t >> 6;
  int wy = wid >> 1, wx = wid & 1;
  int lr = lane & 15;
  int lk2 = (((lane >> 4) ^ ((lane >> 1) & 3)) << 3);
  int crow = lane >> 2;
  int celsw = (((lane & 3) ^ ((lane >> 3) & 3)) << 3);
  int c0 = wid << 1;

  const unsigned short* pa0 = Ahi + (size_t)(mbase + (c0 << 4) + crow) * lda + celsw;
  const unsigned short* pa1 = pa0 + (size_t)16 * lda;
  const unsigned short* pb0 = Bhi + (size_t)(nbase + (c0 << 4) + crow) * ldb + bkoff + celsw;
  const unsigned short* pb1 = pb0 + (size_t)16 * ldb;
  unsigned short* dA0 = &sA[(size_t)c0 << 9];
  unsigned short* dA1 = &sA[(size_t)(c0 + 1) << 9];
  unsigned short* dB0 = &sB[(size_t)c0 << 9];
  unsigned short* dB1 = &sB[(size_t)(c0 + 1) << 9];

  f32x4 zero = {0.f, 0.f, 0.f, 0.f};
  f32x4 acc[4][4];
  for (int i = 0; i < 4; i++)
    for (int j = 0; j < 4; j++) acc[i][j] = zero;

  for (int k0 = 0; k0 < HDIM; k0 += 32) {
    gload16(pa0 + k0, dA0);
    gload16(pa1 + k0, dA1);
    gload16(pb0 + k0, dB0);
    gload16(pb1 + k0, dB1);
    __syncthreads();
    f16x8 ah[4], bh[4];
    for (int i = 0; i < 4; i++) {
      int ar = (wy << 6) + (i << 4) + lr;
      int br = (wx << 6) + (i << 4) + lr;
      ah[i] = *reinterpret_cast<const f16x8*>(&sA[ar * 32 + lk2]);
      bh[i] = *reinterpret_cast<const f16x8*>(&sB[br * 32 + lk2]);
    }
    for (int i = 0; i < 4; i++)
      for (int j = 0; j < 4; j++)
        acc[i][j] = __builtin_amdgcn_mfma_f32_16x16x32_f16(ah[i], bh[j], acc[i][j], 0, 0, 0);
    __syncthreads();
  }

  int q = lane >> 4, cc = lane & 15;
  for (int i = 0; i < 4; i++)
    for (int r = 0; r < 4; r++) {
      int grow = mbase + (wy << 6) + (i << 4) + (q << 2) + r;
      for (int j = 0; j < 4; j++) {
        int gcol = nbase + (wx << 6) + (j << 4) + cc;
        Dout[(size_t)grow * ldd + gcol] = acc[i][j][r];
      }
    }
}

// ---------------- SIM: 256x256, 8 waves, 2 LDS bufs, cross-phase read prefetch ----------------
// Per tile: HH / HL / LH clusters (32 MFMA each). Reads for a cluster are always issued
// one cluster earlier (bl/al before the vmcnt+bar; ah' under LH-1; bh' under next HH-1),
// so ds latency hides under MFMA. vmcnt(0) mid-iter drains exactly tile tt+1's 8 gloads
// issued a full iteration earlier. 2 barriers/tile.
__global__ __launch_bounds__(512, 2) void gemm256_sim(
    const unsigned short* __restrict__ Ahi, const unsigned short* __restrict__ Alo,
    const unsigned short* __restrict__ Bhi, const unsigned short* __restrict__ Blo,
    int lda, int ldb, int NT,
    unsigned long long* __restrict__ keys) {
  // per buf (ushorts): AH 8192 | AL 8192 | BH 8192 | BL 8192 ; 2 bufs = 128 KB
  __shared__ unsigned short lds[65536];
  constexpr int AH = 0, AL = 8192, BH = 16384, BL = 24576, BUF = 32768;

  int t = threadIdx.x;
  int bidx = blockIdx.x;
  int xcd = bidx & 7, slot = bidx >> 3;
  int nt = slot % NT, mt = (slot / NT) * 8 + xcd;  // nmt = 128, multiple of 8
  int mbase = mt << 8, nbase = nt << 8;
  int lane = t & 63, wid = t >> 6;
  int wy = wid >> 2, wx = wid & 3;  // 2 x 4 wave grid; wave tile 128 x 64
  int lr = lane & 15;
  int lk2 = (((lane >> 4) ^ ((lane >> 1) & 3)) << 3);

  int srow = (wid << 4) + (lane >> 2);
  int scol = (((lane & 3) ^ ((lane >> 3) & 3)) << 3);
  int wdst = wid << 9;

  const unsigned short* gAh = Ahi + (size_t)(mbase + srow) * lda + scol;
  const unsigned short* gBh = Bhi + (size_t)(nbase + srow) * ldb + scol;
  const unsigned short* gAl = Alo + (gAh - Ahi);
  const unsigned short* gBl = Blo + (gBh - Bhi);
  const size_t a128 = (size_t)128 * lda, b128 = (size_t)128 * ldb;

  auto STAGE = [&](int k0v, int cb) {
    int co = cb * BUF;
    gload16(gAh + k0v, &lds[AH + co + wdst]);
    gload16(gAh + a128 + k0v, &lds[AH + co + 4096 + wdst]);
    gload16(gBh + k0v, &lds[BH + co + wdst]);
    gload16(gBh + b128 + k0v, &lds[BH + co + 4096 + wdst]);
    gload16(gBl + k0v, &lds[BL + co + wdst]);
    gload16(gBl + b128 + k0v, &lds[BL + co + 4096 + wdst]);
    gload16(gAl + k0v, &lds[AL + co + wdst]);
    gload16(gAl + a128 + k0v, &lds[AL + co + 4096 + wdst]);
  };

  int arowb = (((wy << 7) + lr) << 5) + lk2;  // + i*512
  int browb = (((wx << 6) + lr) << 5) + lk2;  // + j*512

  f32x4 zero = {0.f, 0.f, 0.f, 0.f};
  f32x4 acc[8][4];
#pragma unroll
  for (int i = 0; i < 8; i++)
#pragma unroll
    for (int j = 0; j < 4; j++) acc[i][j] = zero;

  STAGE(0, 0);
  STAGE(32, 1);
  WAITVM(8);  // tile0's 8 done (tile1's 8 outstanding)
  BAR();

  f16x8 ah[8], bh[4], al[8], bl[4];
#pragma unroll
  for (int i = 0; i < 8; i++)
    ah[i] = *reinterpret_cast<const f16x8*>(&lds[AH + arowb + (i << 9)]);
#pragma unroll
  for (int j = 0; j < 4; j++)
    bh[j] = *reinterpret_cast<const f16x8*>(&lds[BH + browb + (j << 9)]);

  for (int tt = 0; tt < 32; ++tt) {
    int co = (tt & 1) * BUF;
    int cn = ((tt + 1) & 1) * BUF;
    LGKM(0);  // ah,bh(tt) ready (only their reads outstanding)
    __builtin_amdgcn_s_setprio(1);
#pragma unroll
    for (int i = 0; i < 8; i++)
#pragma unroll
      for (int j = 0; j < 4; j++)
        acc[i][j] = __builtin_amdgcn_mfma_f32_16x16x32_f16(ah[i], bh[j], acc[i][j], 0, 0, 0);
    __builtin_amdgcn_s_setprio(0);
    SCHED0();
    // issue bl, al for this tile (latency hides under the vmcnt/bar + HL wait slack)
#pragma unroll
    for (int j = 0; j < 4; j++)
      bl[j] = *reinterpret_cast<const f16x8*>(&lds[BL + co + browb + (j << 9)]);
#pragma unroll
    for (int i = 0; i < 8; i++)
      al[i] = *reinterpret_cast<const f16x8*>(&lds[AL + co + arowb + (i << 9)]);
    WAITVM(0);  // tile tt+1's gloads (issued end of iter tt-1) complete
    BAR();      // all waves: tile tt+1 staged; ah/bh(tt) regs consumed
    LGKM(8);    // bl done (al may be in flight)
    __builtin_amdgcn_s_setprio(1);
#pragma unroll
    for (int i = 0; i < 8; i++)
#pragma unroll
      for (int j = 0; j < 4; j++)
        acc[i][j] = __builtin_amdgcn_mfma_f32_16x16x32_f16(ah[i], bl[j], acc[i][j], 0, 0, 0);
    __builtin_amdgcn_s_setprio(0);
    SCHED0();
    if (tt < 31) {  // prefetch next tile's A-hi under the LH cluster (ah dead after HL)
#pragma unroll
      for (int i = 0; i < 8; i++)
        ah[i] = *reinterpret_cast<const f16x8*>(&lds[AH + cn + arowb + (i << 9)]);
      LGKM(8);  // al done (ah' reads are the 8 newest)
    } else {
      LGKM(0);
    }
    __builtin_amdgcn_s_setprio(1);
#pragma unroll
    for (int i = 0; i < 8; i++)
#pragma unroll
      for (int j = 0; j < 4; j++)
        acc[i][j] = __builtin_amdgcn_mfma_f32_16x16x32_f16(al[i], bh[j], acc[i][j], 0, 0, 0);
    __builtin_amdgcn_s_setprio(0);
    SCHED0();
    if (tt < 31) {  // prefetch next tile's B-hi (bh dead after LH)
#pragma unroll
      for (int j = 0; j < 4; j++)
        bh[j] = *reinterpret_cast<const f16x8*>(&lds[BH + cn + browb + (j << 9)]);
    }
    BAR();  // all waves done reading buf co -> safe to restage
    if (tt < 30) STAGE((tt + 2) << 5, tt & 1);
  }

  int q = lane >> 4, cc = lane & 15;
  int wrowb = mbase + (wy << 7), wcolb = nbase + (wx << 6);
#pragma unroll
  for (int i = 0; i < 8; i++)
#pragma unroll
    for (int r = 0; r < 4; r++) {
      int grow = wrowb + (i << 4) + (q << 2) + r;
      unsigned long long best = 0ull;
#pragma unroll
      for (int j = 0; j < 4; j++) {
        float vv = acc[i][j][r];
        unsigned vb = __float_as_uint(vv);
        vb = (vb & 0x80000000u) ? ~vb : (vb | 0x80000000u);
        unsigned idxn = (unsigned)(wcolb + (j << 4) + cc);
        unsigned long long key = ((unsigned long long)vb << 32) | (unsigned)(~idxn);
        if (key > best) best = key;
      }
      for (int m = 1; m <= 8; m <<= 1) {
        unsigned long long o = shfl_xor_u64(best, m);
        if (o > best) best = o;
      }
      if (cc == 0) atomicMax(keys + grow, best);
    }
}

// ---------------- MAIN: 256x256, 8 waves, 3 LDS bufs, double reg set ----------------
// Per tile: 32 MFMA. nxt-tile ds_reads issue before the MFMA cluster (latency under
// MFMA); gloads prefetched 2-3 tiles deep with counted vmcnt(4). 2 barriers/tile.
__global__ __launch_bounds__(512, 2) void gemm256_main(
    const unsigned short* __restrict__ Ahi, const unsigned short* __restrict__ Bhi,
    int lda, int ldb, int bkoff, int NT,
    const unsigned long long* __restrict__ keys,
    const float* __restrict__ aproj,
    float* __restrict__ out) {
  // per buf (ushorts): AH 8192 | BH 8192 ; 3 bufs = 96 KB
  __shared__ unsigned short lds[49152];
  constexpr int AH = 0, BH = 8192, BUF = 16384;

  int t = threadIdx.x;
  int bidx = blockIdx.x;
  int xcd = bidx & 7, slot = bidx >> 3;
  int nt = slot % NT, mt = (slot / NT) * 8 + xcd;
  int mbase = mt << 8, nbase = nt << 8;
  int lane = t & 63, wid = t >> 6;
  int wy = wid >> 2, wx = wid & 3;
  int lr = lane & 15;
  int lk2 = (((lane >> 4) ^ ((lane >> 1) & 3)) << 3);

  int srow = (wid << 4) + (lane >> 2);
  int scol = (((lane & 3) ^ ((lane >> 3) & 3)) << 3);
  int wdst = wid << 9;

  const unsigned short* gAh = Ahi + (size_t)(mbase + srow) * lda + scol;
  const unsigned short* gBh = Bhi + (size_t)(nbase + srow) * ldb + bkoff + scol;
  const size_t a128 = (size_t)128 * lda, b128 = (size_t)128 * ldb;

  auto STAGE = [&](int k0v, int b) {
    int co = b * BUF;
    gload16(gAh + k0v, &lds[AH + co + wdst]);
    gload16(gAh + a128 + k0v, &lds[AH + co + 4096 + wdst]);
    gload16(gBh + k0v, &lds[BH + co + wdst]);
    gload16(gBh + b128 + k0v, &lds[BH + co + 4096 + wdst]);
  };

  int arowb = (((wy << 7) + lr) << 5) + lk2;
  int browb = (((wx << 6) + lr) << 5) + lk2;

  f32x4 zero = {0.f, 0.f, 0.f, 0.f};
  f32x4 acc[8][4];
#pragma unroll
  for (int i = 0; i < 8; i++)
#pragma unroll
    for (int j = 0; j < 4; j++) acc[i][j] = zero;

  STAGE(0, 0);
  STAGE(32, 1);
  STAGE(64, 2);
  WAITVM(8);  // tile0 done
  BAR();

  f16x8 aX[8], bX[4], aY[8], bY[4];
#pragma unroll
  for (int i = 0; i < 8; i++)
    aX[i] = *reinterpret_cast<const f16x8*>(&lds[AH + arowb + (i << 9)]);
#pragma unroll
  for (int j = 0; j < 4; j++)
    bX[j] = *reinterpret_cast<const f16x8*>(&lds[BH + browb + (j << 9)]);

  auto ITER = [&](int tt, f16x8 (&ac)[8], f16x8 (&bc)[4], f16x8 (&an)[8], f16x8 (&bn)[4]) {
    // vmcnt: steady outstanding = STAGE(tt+1)+STAGE(tt+2) = 8 -> wait<=4 => tt+1 done
    if (tt < 30) { WAITVM(4); } else { WAITVM(0); }
    BAR();  // all waves: tile tt+1 staged; cur-reads of buf tt%3 were issued last iter
    if (tt < 31) {
      int cn = ((tt + 1) % 3) * BUF;
#pragma unroll
      for (int i = 0; i < 8; i++)
        an[i] = *reinterpret_cast<const f16x8*>(&lds[AH + cn + arowb + (i << 9)]);
#pragma unroll
      for (int j = 0; j < 4; j++)
        bn[j] = *reinterpret_cast<const f16x8*>(&lds[BH + cn + browb + (j << 9)]);
      LGKM(12);  // cur regs ready (their reads precede the 12 just issued)
    } else {
      LGKM(0);
    }
    __builtin_amdgcn_s_setprio(1);
#pragma unroll
    for (int i = 0; i < 8; i++)
#pragma unroll
      for (int j = 0; j < 4; j++)
        acc[i][j] = __builtin_amdgcn_mfma_f32_16x16x32_f16(ac[i], bc[j], acc[i][j], 0, 0, 0);
    __builtin_amdgcn_s_setprio(0);
    SCHED0();
    BAR();  // all waves' cur-reads of buf tt%3 complete -> safe to restage it
    if (tt < 29) STAGE((tt + 3) << 5, tt % 3);
  };

  for (int t2 = 0; t2 < 16; ++t2) {
    ITER(2 * t2, aX, bX, aY, bY);
    ITER(2 * t2 + 1, aY, bY, aX, bX);
  }

  int q = lane >> 4, cc = lane & 15;
  int wrowb = mbase + (wy << 7), wcolb = nbase + (wx << 6);
#pragma unroll
  for (int i = 0; i < 8; i++)
#pragma unroll
    for (int r = 0; r < 4; r++) {
      int grow = wrowb + (i << 4) + (q << 2) + r;
      unsigned idx = ~(unsigned)(keys[grow] & 0xFFFFFFFFull);
      idx &= 1023u;
      const float* ap = aproj + (size_t)idx * NOUT;
#pragma unroll
      for (int j = 0; j < 4; j++) {
        int gcol = wcolb + (j << 4) + cc;
        out[(size_t)grow * NOUT + gcol] = acc[i][j][r] + ap[gcol];
      }
    }
}

extern "C" void kernel_launch(void* const* d_in, const int* in_sizes, int n_in,
                              void* d_out, int out_size, void* d_ws, size_t ws_size,
                              hipStream_t stream) {
  const float* features = (const float*)d_in[0];
  const float* anchors = (const float*)d_in[1];
  const float* Wout = (const float*)d_in[2];
  float* out = (float*)d_out;

  char* p = (char*)d_ws;
  size_t off = 0;
  auto alloc = [&](size_t b) {
    char* r = p + off;
    off += (b + 255) & ~(size_t)255;
    return r;
  };
  unsigned short* fh = (unsigned short*)alloc((size_t)N_ROWS * HDIM * 2);
  unsigned short* fl = (unsigned short*)alloc((size_t)N_ROWS * HDIM * 2);
  unsigned short* ash = (unsigned short*)alloc((size_t)CPAD * HDIM * 2);
  unsigned short* asl = (unsigned short*)alloc((size_t)CPAD * HDIM * 2);
  unsigned short* anh = (unsigned short*)alloc((size_t)CPAD * HDIM * 2);
  unsigned short* wt = (unsigned short*)alloc((size_t)NOUT * KK2 * 2);
  float* ap = (float*)alloc((size_t)CPAD * NOUT * 4);
  unsigned long long* keys = (unsigned long long*)alloc((size_t)N_ROWS * 8);
  if (off > ws_size) return;

  init_keys_kernel<<<N_ROWS / 256, 256, 0, stream>>>(keys);
  prep_anchors_kernel<<<CPAD, 256, 0, stream>>>(anchors, ash, asl, anh);
  fsplit_kernel<<<(N_ROWS * HDIM / 4) / 256, 256, 0, stream>>>(features, fh, fl);
  wtrans_kernel<<<512, 256, 0, stream>>>(Wout, wt);
  // anchor_proj = class_anchors @ W[0:1024,:] -> ap
  gemm_out_kernel<<<64, 256, 0, stream>>>(anh, wt, HDIM, KK2, 0, 8, ap, NOUT);
  // sim + argmax (3-term fp16 split)
  gemm256_sim<<<512, 512, 0, stream>>>(fh, fl, ash, asl, HDIM, HDIM, 4, keys);
  // out = features @ W[1024:2048,:] + anchor_proj[idx]
  gemm256_main<<<512, 512, 0, stream>>>(fh, wt, HDIM, KK2, HDIM, 4, keys, ap, out);
}